// Round 1
// baseline (2068.834 us; speedup 1.0000x reference)
//
#include <hip/hip_runtime.h>

// Problem constants (from reference)
#define U_CNT 100000
#define I_CNT 50000
#define N_CNT 150000   // U + I
#define D_CNT 64
#define NNZ_CNT 1000000

// Output flat layout (floats):
//   user_all     [U*64]          @ 0
//   item_all     [I*64]          @ 6,400,000
//   stacked      [N*4*64]        @ 9,600,000   (row stride 256; slots 0..3 of 64)
//   path_stacked [N*4*64]        @ 48,000,000
#define OFF_ITEM   6400000LL
#define OFF_STACK  9600000LL
#define OFF_PATH   48000000LL

// Zero slot-1 (the SpMM accumulator) of both stacked and path_stacked.
// One float4 per thread per array.
__global__ void zero_slot1_k(float* __restrict__ out) {
    int t = blockIdx.x * blockDim.x + threadIdx.x;
    if (t >= N_CNT * 16) return;
    int n = t >> 4, q = t & 15;
    long long off = (long long)n * 256 + 64 + (long long)q * 4;
    float4 z = make_float4(0.f, 0.f, 0.f, 0.f);
    *(float4*)(out + OFF_STACK + off) = z;
    *(float4*)(out + OFF_PATH  + off) = z;
}

// COO SpMM scatter: acc[rows[e]] += vals[e] * ego[cols[e]]
// 16 threads per edge, each thread owns one float4 of the 64-float row.
// acc points at slot-1 of row 0 (row stride = 256 floats).
__global__ void scatter_k(const int*   __restrict__ rows,
                          const int*   __restrict__ cols,
                          const float* __restrict__ vals,
                          const float* __restrict__ user_emb,
                          const float* __restrict__ item_emb,
                          float* __restrict__ acc) {
    long long t = (long long)blockIdx.x * blockDim.x + threadIdx.x;
    int e = (int)(t >> 4);
    if (e >= NNZ_CNT) return;
    int q = (int)(t & 15);
    int r = rows[e];
    int c = cols[e];
    float v = vals[e];
    const float* src = (c < U_CNT) ? (user_emb + (long long)c * D_CNT)
                                   : (item_emb + (long long)(c - U_CNT) * D_CNT);
    float4 x = *(const float4*)(src + q * 4);
    float* dst = acc + (long long)r * 256 + q * 4;
    atomicAdd(dst + 0, v * x.x);
    atomicAdd(dst + 1, v * x.y);
    atomicAdd(dst + 2, v * x.z);
    atomicAdd(dst + 3, v * x.w);
}

// Finalize: write ego to slot0, replicate slot1 -> slots 2,3 for both arrays,
// and write mean = 0.25*ego + 0.75*Aego into user_all/item_all.
__global__ void finalize_k(const float* __restrict__ user_emb,
                           const float* __restrict__ item_emb,
                           float* __restrict__ out) {
    int t = blockIdx.x * blockDim.x + threadIdx.x;
    if (t >= N_CNT * 16) return;
    int n = t >> 4, q = t & 15;
    const float* src = (n < U_CNT) ? (user_emb + (long long)n * D_CNT)
                                   : (item_emb + (long long)(n - U_CNT) * D_CNT);
    float4 e4 = *(const float4*)(src + q * 4);

    float* st = out + OFF_STACK + (long long)n * 256;
    float* pt = out + OFF_PATH  + (long long)n * 256;
    float4 a4 = *(const float4*)(st + 64 + q * 4);
    float4 r4 = *(const float4*)(pt + 64 + q * 4);

    float4 m4 = make_float4(0.25f * e4.x + 0.75f * a4.x,
                            0.25f * e4.y + 0.75f * a4.y,
                            0.25f * e4.z + 0.75f * a4.z,
                            0.25f * e4.w + 0.75f * a4.w);

    *(float4*)(st + q * 4)       = e4;  // slot 0
    *(float4*)(st + 128 + q * 4) = a4;  // slot 2
    *(float4*)(st + 192 + q * 4) = a4;  // slot 3
    *(float4*)(pt + q * 4)       = e4;  // slot 0
    *(float4*)(pt + 128 + q * 4) = r4;  // slot 2
    *(float4*)(pt + 192 + q * 4) = r4;  // slot 3

    float* md = (n < U_CNT) ? (out + (long long)n * D_CNT)
                            : (out + OFF_ITEM + (long long)(n - U_CNT) * D_CNT);
    *(float4*)(md + q * 4) = m4;
}

extern "C" void kernel_launch(void* const* d_in, const int* in_sizes, int n_in,
                              void* d_out, int out_size, void* d_ws, size_t ws_size,
                              hipStream_t stream) {
    const float* user_emb  = (const float*)d_in[0];
    const float* item_emb  = (const float*)d_in[1];
    const int*   adj_rows  = (const int*)d_in[2];
    const int*   adj_cols  = (const int*)d_in[3];
    const float* adj_vals  = (const float*)d_in[4];
    const int*   radj_rows = (const int*)d_in[5];
    const int*   radj_cols = (const int*)d_in[6];
    const float* radj_vals = (const float*)d_in[7];
    float* out = (float*)d_out;

    const int BLK = 256;
    int zgrid = (N_CNT * 16 + BLK - 1) / BLK;          // 9375
    int sgrid = (int)(((long long)NNZ_CNT * 16 + BLK - 1) / BLK);  // 62500

    zero_slot1_k<<<zgrid, BLK, 0, stream>>>(out);

    scatter_k<<<sgrid, BLK, 0, stream>>>(adj_rows, adj_cols, adj_vals,
                                         user_emb, item_emb,
                                         out + OFF_STACK + 64);
    scatter_k<<<sgrid, BLK, 0, stream>>>(radj_rows, radj_cols, radj_vals,
                                         user_emb, item_emb,
                                         out + OFF_PATH + 64);

    finalize_k<<<zgrid, BLK, 0, stream>>>(user_emb, item_emb, out);
}

// Round 2
// 768.236 us; speedup vs baseline: 2.6930x; 2.6930x over previous
//
#include <hip/hip_runtime.h>

#define U_CNT 100000
#define I_CNT 50000
#define N_CNT 150000
#define D_CNT 64
#define NNZ_CNT 1000000

#define OFF_ITEM   6400000LL
#define OFF_STACK  9600000LL
#define OFF_PATH   48000000LL

#define CPAD 150016           // padded row-count stride (ints)
#define SCAN_B 1024
#define NB 147                // ceil(150000/1024)

// ---------------- CSR-build path ----------------

__global__ void zero_cnt_k(int* __restrict__ cnt_a, int* __restrict__ cnt_r) {
    int i = blockIdx.x * blockDim.x + threadIdx.x;
    if (i < N_CNT) { cnt_a[i] = 0; cnt_r[i] = 0; }
}

__global__ void hist_k(const int* __restrict__ arows, const int* __restrict__ rrows,
                       int* __restrict__ cnt_a, int* __restrict__ cnt_r) {
    int e = blockIdx.x * blockDim.x + threadIdx.x;
    if (e >= NNZ_CNT) return;
    atomicAdd(cnt_a + arows[e], 1);
    atomicAdd(cnt_r + rrows[e], 1);
}

// per-block sums of counts -> part[y*256 + b]
__global__ void scan1_k(const int* __restrict__ cnt_a, const int* __restrict__ cnt_r,
                        int* __restrict__ part) {
    __shared__ int s[SCAN_B];
    const int* cnt = blockIdx.y ? cnt_r : cnt_a;
    int i = blockIdx.x * SCAN_B + threadIdx.x;
    s[threadIdx.x] = (i < N_CNT) ? cnt[i] : 0;
    __syncthreads();
    for (int d = SCAN_B >> 1; d > 0; d >>= 1) {
        if (threadIdx.x < d) s[threadIdx.x] += s[threadIdx.x + d];
        __syncthreads();
    }
    if (threadIdx.x == 0) part[blockIdx.y * 256 + blockIdx.x] = s[0];
}

// exclusive scan of the NB partials for each array (tiny, sequential)
__global__ void scan2_k(int* __restrict__ part) {
    int y = threadIdx.x;
    if (y >= 2) return;
    int* p = part + y * 256;
    int run = 0;
    for (int i = 0; i < NB; ++i) { int v = p[i]; p[i] = run; run += v; }
}

// block-level exclusive scan + partial offset -> off[], cur[]
__global__ void scan3_k(const int* __restrict__ cnt_a, const int* __restrict__ cnt_r,
                        const int* __restrict__ part,
                        int* __restrict__ off_a, int* __restrict__ off_r,
                        int* __restrict__ cur_a, int* __restrict__ cur_r) {
    __shared__ int s[SCAN_B];
    const int* cnt = blockIdx.y ? cnt_r : cnt_a;
    int*       off = blockIdx.y ? off_r : off_a;
    int*       cur = blockIdx.y ? cur_r : cur_a;
    int i = blockIdx.x * SCAN_B + threadIdx.x;
    int v = (i < N_CNT) ? cnt[i] : 0;
    s[threadIdx.x] = v;
    __syncthreads();
    // Hillis-Steele inclusive scan
    for (int d = 1; d < SCAN_B; d <<= 1) {
        int x = (threadIdx.x >= d) ? s[threadIdx.x - d] : 0;
        __syncthreads();
        s[threadIdx.x] += x;
        __syncthreads();
    }
    if (i < N_CNT) {
        int excl = s[threadIdx.x] - v + part[blockIdx.y * 256 + blockIdx.x];
        off[i] = excl;
        cur[i] = excl;
    }
}

__global__ void reorder_k(const int* __restrict__ arows, const int* __restrict__ acols,
                          const float* __restrict__ avals,
                          const int* __restrict__ rrows, const int* __restrict__ rcols,
                          const float* __restrict__ rvals,
                          int* __restrict__ cur_a, int* __restrict__ cur_r,
                          int2* __restrict__ ed_a, int2* __restrict__ ed_r) {
    int e = blockIdx.x * blockDim.x + threadIdx.x;
    if (e >= NNZ_CNT) return;
    const int*   rows = blockIdx.y ? rrows : arows;
    const int*   colsp = blockIdx.y ? rcols : acols;
    const float* vals = blockIdx.y ? rvals : avals;
    int*  cur   = blockIdx.y ? cur_r : cur_a;
    int2* edges = blockIdx.y ? ed_r : ed_a;
    int r = rows[e];
    int pos = atomicAdd(cur + r, 1);
    edges[pos] = make_int2(colsp[e], __float_as_int(vals[e]));
}

// One wave per row (64 lanes = 64 dims). blockIdx.y: 0 = adj (stacked+mean), 1 = radj (path).
__global__ __launch_bounds__(256) void spmm_fin_k(
    const int* __restrict__ off_a, const int* __restrict__ cnt_a,
    const int* __restrict__ off_r, const int* __restrict__ cnt_r,
    const int2* __restrict__ ed_a, const int2* __restrict__ ed_r,
    const float* __restrict__ user_emb, const float* __restrict__ item_emb,
    float* __restrict__ out) {
    int wave = blockIdx.x * (blockDim.x >> 6) + (threadIdx.x >> 6);
    int lane = threadIdx.x & 63;
    if (wave >= N_CNT) return;
    int which = blockIdx.y;
    const int*  off   = which ? off_r : off_a;
    const int*  cnt   = which ? cnt_r : cnt_a;
    const int2* edges = which ? ed_r : ed_a;

    int o = off[wave], c = cnt[wave];
    float acc = 0.f;
    for (int base = 0; base < c; base += 64) {
        int m = min(64, c - base);
        int2 ev = make_int2(0, 0);
        if (lane < m) ev = edges[o + base + lane];
        for (int j = 0; j < m; ++j) {
            int   col = __shfl(ev.x, j);
            float v   = __int_as_float(__shfl(ev.y, j));
            const float* src = (col < U_CNT) ? (user_emb + (long long)col * D_CNT)
                                             : (item_emb + (long long)(col - U_CNT) * D_CNT);
            acc += v * src[lane];
        }
    }

    const float* esrc = (wave < U_CNT) ? (user_emb + (long long)wave * D_CNT)
                                       : (item_emb + (long long)(wave - U_CNT) * D_CNT);
    float e = esrc[lane];
    long long rb = (which ? OFF_PATH : OFF_STACK) + (long long)wave * 256;
    out[rb + lane]       = e;
    out[rb + 64 + lane]  = acc;
    out[rb + 128 + lane] = acc;
    out[rb + 192 + lane] = acc;
    if (which == 0) {
        float mv = 0.25f * e + 0.75f * acc;
        long long mb = (wave < U_CNT) ? (long long)wave * D_CNT
                                      : OFF_ITEM + (long long)(wave - U_CNT) * D_CNT;
        out[mb + lane] = mv;
    }
}

// ---------------- fallback atomic path (round-1) ----------------

__global__ void zero_slot1_k(float* __restrict__ out) {
    int t = blockIdx.x * blockDim.x + threadIdx.x;
    if (t >= N_CNT * 16) return;
    int n = t >> 4, q = t & 15;
    long long off = (long long)n * 256 + 64 + (long long)q * 4;
    float4 z = make_float4(0.f, 0.f, 0.f, 0.f);
    *(float4*)(out + OFF_STACK + off) = z;
    *(float4*)(out + OFF_PATH  + off) = z;
}

__global__ void scatter_k(const int* __restrict__ rows, const int* __restrict__ cols,
                          const float* __restrict__ vals,
                          const float* __restrict__ user_emb, const float* __restrict__ item_emb,
                          float* __restrict__ acc) {
    long long t = (long long)blockIdx.x * blockDim.x + threadIdx.x;
    int e = (int)(t >> 4);
    if (e >= NNZ_CNT) return;
    int q = (int)(t & 15);
    int r = rows[e];
    int c = cols[e];
    float v = vals[e];
    const float* src = (c < U_CNT) ? (user_emb + (long long)c * D_CNT)
                                   : (item_emb + (long long)(c - U_CNT) * D_CNT);
    float4 x = *(const float4*)(src + q * 4);
    float* dst = acc + (long long)r * 256 + q * 4;
    atomicAdd(dst + 0, v * x.x);
    atomicAdd(dst + 1, v * x.y);
    atomicAdd(dst + 2, v * x.z);
    atomicAdd(dst + 3, v * x.w);
}

__global__ void finalize_k(const float* __restrict__ user_emb,
                           const float* __restrict__ item_emb,
                           float* __restrict__ out) {
    int t = blockIdx.x * blockDim.x + threadIdx.x;
    if (t >= N_CNT * 16) return;
    int n = t >> 4, q = t & 15;
    const float* src = (n < U_CNT) ? (user_emb + (long long)n * D_CNT)
                                   : (item_emb + (long long)(n - U_CNT) * D_CNT);
    float4 e4 = *(const float4*)(src + q * 4);
    float* st = out + OFF_STACK + (long long)n * 256;
    float* pt = out + OFF_PATH  + (long long)n * 256;
    float4 a4 = *(const float4*)(st + 64 + q * 4);
    float4 r4 = *(const float4*)(pt + 64 + q * 4);
    float4 m4 = make_float4(0.25f * e4.x + 0.75f * a4.x, 0.25f * e4.y + 0.75f * a4.y,
                            0.25f * e4.z + 0.75f * a4.z, 0.25f * e4.w + 0.75f * a4.w);
    *(float4*)(st + q * 4)       = e4;
    *(float4*)(st + 128 + q * 4) = a4;
    *(float4*)(st + 192 + q * 4) = a4;
    *(float4*)(pt + q * 4)       = e4;
    *(float4*)(pt + 128 + q * 4) = r4;
    *(float4*)(pt + 192 + q * 4) = r4;
    float* md = (n < U_CNT) ? (out + (long long)n * D_CNT)
                            : (out + OFF_ITEM + (long long)(n - U_CNT) * D_CNT);
    *(float4*)(md + q * 4) = m4;
}

extern "C" void kernel_launch(void* const* d_in, const int* in_sizes, int n_in,
                              void* d_out, int out_size, void* d_ws, size_t ws_size,
                              hipStream_t stream) {
    const float* user_emb  = (const float*)d_in[0];
    const float* item_emb  = (const float*)d_in[1];
    const int*   adj_rows  = (const int*)d_in[2];
    const int*   adj_cols  = (const int*)d_in[3];
    const float* adj_vals  = (const float*)d_in[4];
    const int*   radj_rows = (const int*)d_in[5];
    const int*   radj_cols = (const int*)d_in[6];
    const float* radj_vals = (const float*)d_in[7];
    float* out = (float*)d_out;
    const int BLK = 256;

    // ws layout (ints): cnt_a, cnt_r, off_a, off_r, cur_a, cur_r (CPAD each),
    // part[512], then int2 ed_a[1M], ed_r[1M]
    size_t need = (size_t)(6 * CPAD + 512) * 4 + (size_t)2 * NNZ_CNT * 8;
    if (ws_size >= need) {
        int* cnt_a = (int*)d_ws;
        int* cnt_r = cnt_a + CPAD;
        int* off_a = cnt_r + CPAD;
        int* off_r = off_a + CPAD;
        int* cur_a = off_r + CPAD;
        int* cur_r = cur_a + CPAD;
        int* part  = cur_r + CPAD;
        int2* ed_a = (int2*)(part + 512);
        int2* ed_r = ed_a + NNZ_CNT;

        zero_cnt_k<<<(N_CNT + BLK - 1) / BLK, BLK, 0, stream>>>(cnt_a, cnt_r);
        hist_k<<<(NNZ_CNT + BLK - 1) / BLK, BLK, 0, stream>>>(adj_rows, radj_rows, cnt_a, cnt_r);
        scan1_k<<<dim3(NB, 2), SCAN_B, 0, stream>>>(cnt_a, cnt_r, part);
        scan2_k<<<1, 64, 0, stream>>>(part);
        scan3_k<<<dim3(NB, 2), SCAN_B, 0, stream>>>(cnt_a, cnt_r, part,
                                                    off_a, off_r, cur_a, cur_r);
        reorder_k<<<dim3((NNZ_CNT + BLK - 1) / BLK, 2), BLK, 0, stream>>>(
            adj_rows, adj_cols, adj_vals, radj_rows, radj_cols, radj_vals,
            cur_a, cur_r, ed_a, ed_r);
        int waves_per_blk = BLK / 64;
        spmm_fin_k<<<dim3((N_CNT + waves_per_blk - 1) / waves_per_blk, 2), BLK, 0, stream>>>(
            off_a, cnt_a, off_r, cnt_r, ed_a, ed_r, user_emb, item_emb, out);
    } else {
        int zgrid = (N_CNT * 16 + BLK - 1) / BLK;
        int sgrid = (int)(((long long)NNZ_CNT * 16 + BLK - 1) / BLK);
        zero_slot1_k<<<zgrid, BLK, 0, stream>>>(out);
        scatter_k<<<sgrid, BLK, 0, stream>>>(adj_rows, adj_cols, adj_vals,
                                             user_emb, item_emb, out + OFF_STACK + 64);
        scatter_k<<<sgrid, BLK, 0, stream>>>(radj_rows, radj_cols, radj_vals,
                                             user_emb, item_emb, out + OFF_PATH + 64);
        finalize_k<<<zgrid, BLK, 0, stream>>>(user_emb, item_emb, out);
    }
}